// Round 6
// baseline (491.815 us; speedup 1.0000x reference)
//
#include <hip/hip_runtime.h>
#include <math.h>

#define BB 16
#define TT 1024
#define SS 2048
#define CC 256
#define EE 256
#define NSUB 103        // (SS-1)/STRIDE + 1
#define MAXS 20
#define STRIDE_ 20
#define XCH 32          // t-chunks for xmean partials (TT/XCH = 32 rows each)

static constexpr float RSQRT2  = 0.70710678118654752440f;   // sqrt(0.5)
static constexpr float SQRT_S  = 45.25483399593904f;        // s*sqrt(1/s) = sqrt(2048)
static constexpr float GNORM   = 0.13298076013381093f;      // 1/(sqrt(2*pi)*3)
static constexpr float INV2S2  = 0.055555555555555555f;     // 1/(2*sigma^2)

typedef __attribute__((ext_vector_type(8))) __bf16 bf16x8;
typedef __attribute__((ext_vector_type(4))) float  f32x4;

__device__ __forceinline__ float wave_sum(float v) {
    #pragma unroll
    for (int o = 32; o; o >>= 1) v += __shfl_down(v, o);
    return v;
}
__device__ __forceinline__ float wave_max(float v) {
    #pragma unroll
    for (int o = 32; o; o >>= 1) v = fmaxf(v, __shfl_down(v, o));
    return v;
}
__device__ __forceinline__ unsigned short f2bf(float f) {   // RNE
    unsigned int u = __float_as_uint(f);
    u = (u + 0x7FFFu + ((u >> 16) & 1u)) >> 16;
    return (unsigned short)u;
}
__device__ __forceinline__ float bf2f(unsigned short s) {
    return __uint_as_float(((unsigned int)s) << 16);
}

#define GLD_LDS16(g, l) __builtin_amdgcn_global_load_lds(                      \
    (const __attribute__((address_space(1))) void*)(g),                        \
    (__attribute__((address_space(3))) void*)(l), 16, 0, 0)

// fp32 -> bf16 cast over three disjoint buffers in one launch.
__global__ __launch_bounds__(256) void k_cast3(
    const float* __restrict__ a,  unsigned short* __restrict__ oa, int na,
    const float* __restrict__ b2, unsigned short* __restrict__ ob, int nb,
    const float* __restrict__ c2, unsigned short* __restrict__ oc, int nc)
{
    int i = blockIdx.x * 256 + threadIdx.x;
    const float* in; unsigned short* out;
    if (i < na)                { in = a;  out = oa; }
    else if (i < na + nb)      { in = b2; out = ob; i -= na; }
    else if (i < na + nb + nc) { in = c2; out = oc; i -= na + nb; }
    else return;
    const float4 v = reinterpret_cast<const float4*>(in)[i];
    union { unsigned short u[4]; unsigned long long v8; } pk;
    pk.u[0] = f2bf(v.x); pk.u[1] = f2bf(v.y);
    pk.u[2] = f2bf(v.z); pk.u[3] = f2bf(v.w);
    reinterpret_cast<unsigned long long*>(out)[i] = pk.v8;
}

// fp32 [Bz][R][Cc] -> bf16 [Bz][Cc][R] transpose. grid (R/64, Cc/64, Bz), 256 thr
__global__ __launch_bounds__(256) void k_transpose_bf16(
    const float* __restrict__ in, unsigned short* __restrict__ out, int R, int Cc)
{
    __shared__ float t[64][65];
    const int b = blockIdx.z;
    const int r0 = blockIdx.x * 64, c0 = blockIdx.y * 64;
    const float* ip = in + (size_t)b * R * Cc;
    unsigned short* op = out + (size_t)b * R * Cc;
    const int tx = threadIdx.x & 63, ty = threadIdx.x >> 6;  // ty in [0,4)
    #pragma unroll
    for (int i = 0; i < 16; ++i)
        t[ty + 4 * i][tx] = ip[(size_t)(r0 + ty + 4 * i) * Cc + c0 + tx];
    __syncthreads();
    #pragma unroll
    for (int i = 0; i < 16; ++i)
        op[(size_t)(c0 + ty + 4 * i) * R + r0 + tx] = f2bf(t[tx][ty + 4 * i]);
}

// ---------------------------------------------------------------------------
// Unified bf16 MFMA GEMM (unchanged from R5): BK=64, XOR-swizzled LDS,
// XCD-chunked bijective blockIdx swizzle. 4 waves, 2x2 wave grid.
// MODE 1: Of = (acc + bias[n] + add[m,n])*RSQRT2
// MODE 2: Ob = bf16((acc + bias[n] + add[m,n])*RSQRT2)
// MODE 3: Ob = bf16(acc*scale)
// ---------------------------------------------------------------------------
template<int BM, int BN, int MODE>
__global__ __launch_bounds__(256) void k_gemm(
    const unsigned short* __restrict__ Abase,
    const unsigned short* __restrict__ Btbase,
    const float* __restrict__ bias, const float* __restrict__ add,
    float* __restrict__ Obase, unsigned short* __restrict__ Obbase,
    int M, int Nn, int K, float scale)
{
    constexpr int BK = 64;
    constexpr int AR = BM / 32;
    constexpr int BR = BN / 32;
    constexpr int WM = BM / 2, WN = BN / 2;
    constexpr int MI = WM / 16, NJ = WN / 16;

    __shared__ unsigned short As[BM * BK];
    __shared__ unsigned short Bs[BN * BK];

    const int nwg = gridDim.x * gridDim.y * gridDim.z;
    int l = blockIdx.x + gridDim.x * (blockIdx.y + gridDim.y * blockIdx.z);
    if ((nwg & 7) == 0) l = (l & 7) * (nwg >> 3) + (l >> 3);
    const int bx = l % gridDim.x; l /= gridDim.x;
    const int by = l % gridDim.y;
    const int b  = l / gridDim.y;

    const int m0 = bx * BM;
    const int n0 = by * BN;
    const unsigned short* A  = Abase  + (size_t)b * M  * K;
    const unsigned short* Bt = Btbase + (size_t)b * Nn * K;

    const int tid  = threadIdx.x;
    const int w    = tid >> 6;
    const int lane = tid & 63;
    const int wm   = w & 1, wn = w >> 1;

    const int sr  = tid >> 3;
    const int skb = ((tid & 7) << 4) ^ ((sr & 7) << 4);
    const unsigned short* ga[AR];
    const unsigned short* gb[BR];
    #pragma unroll
    for (int p = 0; p < AR; ++p)
        ga[p] = A + (size_t)(m0 + p * 32 + sr) * K + (skb >> 1);
    #pragma unroll
    for (int p = 0; p < BR; ++p)
        gb[p] = Bt + (size_t)(n0 + p * 32 + sr) * K + (skb >> 1);

    const int fr = lane & 15;
    const int qb = (lane >> 4) << 4;

    f32x4 acc[MI][NJ];
    #pragma unroll
    for (int i = 0; i < MI; ++i)
        #pragma unroll
        for (int j = 0; j < NJ; ++j)
            acc[i][j] = (f32x4){0.f, 0.f, 0.f, 0.f};

    for (int k0 = 0; k0 < K; k0 += BK) {
        #pragma unroll
        for (int p = 0; p < AR; ++p) GLD_LDS16(ga[p], As + p * 2048 + w * 512);
        #pragma unroll
        for (int p = 0; p < BR; ++p) GLD_LDS16(gb[p], Bs + p * 2048 + w * 512);
        #pragma unroll
        for (int p = 0; p < AR; ++p) ga[p] += BK;
        #pragma unroll
        for (int p = 0; p < BR; ++p) gb[p] += BK;
        __syncthreads();
        #pragma unroll
        for (int c = 0; c < 2; ++c) {
            bf16x8 af[MI], bf[NJ];
            #pragma unroll
            for (int i = 0; i < MI; ++i) {
                const int row = wm * WM + i * 16 + fr;
                const int byt = row * 128 + ((c * 64 + qb) ^ ((row & 7) << 4));
                af[i] = *reinterpret_cast<const bf16x8*>(
                            reinterpret_cast<const char*>(As) + byt);
            }
            #pragma unroll
            for (int j = 0; j < NJ; ++j) {
                const int row = wn * WN + j * 16 + fr;
                const int byt = row * 128 + ((c * 64 + qb) ^ ((row & 7) << 4));
                bf[j] = *reinterpret_cast<const bf16x8*>(
                            reinterpret_cast<const char*>(Bs) + byt);
            }
            #pragma unroll
            for (int i = 0; i < MI; ++i)
                #pragma unroll
                for (int j = 0; j < NJ; ++j)
                    acc[i][j] = __builtin_amdgcn_mfma_f32_16x16x32_bf16(af[i], bf[j], acc[i][j], 0, 0, 0);
        }
        __syncthreads();
    }

    float* Of = (MODE == 0 || MODE == 1) ? Obase + (size_t)b * M * Nn : nullptr;
    unsigned short* Ob = (MODE == 2 || MODE == 3) ? Obbase + (size_t)b * M * Nn : nullptr;
    const int rb = (lane >> 4) * 4;
    #pragma unroll
    for (int i = 0; i < MI; ++i)
        #pragma unroll
        for (int j = 0; j < NJ; ++j) {
            const int n = n0 + wn * WN + j * 16 + fr;
            #pragma unroll
            for (int r2 = 0; r2 < 4; ++r2) {
                const int m = m0 + wm * WM + i * 16 + rb + r2;
                const size_t idx = (size_t)m * Nn + n;
                if (MODE == 0) {
                    Of[idx] = acc[i][j][r2] * scale;
                } else if (MODE == 1) {
                    Of[idx] = (acc[i][j][r2] + bias[n] + add[idx]) * RSQRT2;
                } else if (MODE == 2) {
                    Ob[idx] = f2bf((acc[i][j][r2] + bias[n] + add[idx]) * RSQRT2);
                } else {
                    Ob[idx] = f2bf(acc[i][j][r2] * scale);
                }
            }
        }
}

// ---------------------------------------------------------------------------
// Fused QK^T + row softmax. Block = 32 t-rows x full S=2048; 8 waves, wave w
// owns cols [w*256, w*256+256). Scores live in registers (acc[2][16] f32x4);
// h-tile staged in LDS (XOR-swizzled); keysT B-frags loaded straight to
// registers (L2-resident, no cross-wave sharing exists). Softmax on fp32
// scores; outputs attn fp32 + attnb bf16 directly. grid (TT/32, BB).
// ---------------------------------------------------------------------------
__global__ __launch_bounds__(512) void k_qk_softmax(
    const unsigned short* __restrict__ h,      // [B][T][E] bf16
    const unsigned short* __restrict__ keysT,  // [B][S][E] bf16
    float* __restrict__ attn,                  // [B][T][S] fp32 (output)
    unsigned short* __restrict__ attnb)        // [B][T][S] bf16
{
    __shared__ unsigned short hs[32 * 256];    // 16 KB, swizzled
    __shared__ float red[8 * 32];
    __shared__ float rowred[32];

    // chunked XCD swizzle (nwg = 512, bijective): 64-block chunks per XCD
    int l = blockIdx.x + gridDim.x * blockIdx.y;
    l = (l & 7) * 64 + (l >> 3);
    const int tb = l & 31;           // t-chunk   (gridDim.x = 32)
    const int b  = l >> 5;           // batch

    const int tid = threadIdx.x, w = tid >> 6, lane = tid & 63;
    const int fr = lane & 15;
    const int q8 = (lane >> 4) * 8;      // k elems
    const int qb = q8 * 2;               // k bytes

    // stage h tile (32 rows x 256 k bf16), both-sides XOR swizzle:
    // LDS[row][cb] = global[row][cb ^ ((row&7)<<4)], LDS dest linear.
    {
        const int sr = tid >> 5;                 // row within round (0..15)
        const int cb = (tid & 31) << 4;          // byte col (0..511)
        #pragma unroll
        for (int p = 0; p < 2; ++p) {
            const int row = p * 16 + sr;
            const int scb = cb ^ ((row & 7) << 4);
            const unsigned short* g =
                h + ((size_t)b * TT + tb * 32 + row) * EE + (scb >> 1);
            GLD_LDS16(g, hs + p * 4096 + w * 512);
        }
    }
    __syncthreads();

    const int n0w = w * 256;
    const unsigned short* Kb = keysT + (size_t)b * SS * EE;

    f32x4 acc[2][16];
    #pragma unroll
    for (int i = 0; i < 2; ++i)
        #pragma unroll
        for (int j = 0; j < 16; ++j)
            acc[i][j] = (f32x4){0.f, 0.f, 0.f, 0.f};

    #pragma unroll
    for (int kk = 0; kk < 8; ++kk) {             // K = 256 in 32-chunks
        bf16x8 af[2];
        #pragma unroll
        for (int i = 0; i < 2; ++i) {
            const int row = i * 16 + fr;
            const int byt = row * 512 + ((kk * 64 + qb) ^ ((row & 7) << 4));
            af[i] = *reinterpret_cast<const bf16x8*>(
                        reinterpret_cast<const char*>(hs) + byt);
        }
        #pragma unroll
        for (int c = 0; c < 4; ++c) {
            #pragma unroll
            for (int j2 = 0; j2 < 4; ++j2) {
                const int n = n0w + c * 64 + j2 * 16 + fr;
                const bf16x8 bf = *reinterpret_cast<const bf16x8*>(
                                      Kb + (size_t)n * EE + kk * 32 + q8);
                acc[0][c * 4 + j2] = __builtin_amdgcn_mfma_f32_16x16x32_bf16(
                    af[0], bf, acc[0][c * 4 + j2], 0, 0, 0);
                acc[1][c * 4 + j2] = __builtin_amdgcn_mfma_f32_16x16x32_bf16(
                    af[1], bf, acc[1][c * 4 + j2], 0, 0, 0);
            }
        }
    }

    // ---- softmax on fp32 scores ----
    // lane holds rows {i*16 + rb + r2}, cols {c*64 + j2*16 + fr} of this block
    const int rb = (lane >> 4) * 4;

    float mxr[2][4];
    #pragma unroll
    for (int i = 0; i < 2; ++i)
        #pragma unroll
        for (int r2 = 0; r2 < 4; ++r2) {
            float m = acc[i][0][r2];
            #pragma unroll
            for (int j = 1; j < 16; ++j) m = fmaxf(m, acc[i][j][r2]);
            mxr[i][r2] = m;
        }
    #pragma unroll
    for (int o = 1; o < 16; o <<= 1)
        #pragma unroll
        for (int i = 0; i < 2; ++i)
            #pragma unroll
            for (int r2 = 0; r2 < 4; ++r2)
                mxr[i][r2] = fmaxf(mxr[i][r2], __shfl_xor(mxr[i][r2], o));
    if (fr == 0) {
        #pragma unroll
        for (int i = 0; i < 2; ++i)
            #pragma unroll
            for (int r2 = 0; r2 < 4; ++r2)
                red[w * 32 + i * 16 + rb + r2] = mxr[i][r2];
    }
    __syncthreads();
    if (tid < 32) {
        float m = red[tid];
        #pragma unroll
        for (int ww = 1; ww < 8; ++ww) m = fmaxf(m, red[ww * 32 + tid]);
        rowred[tid] = m;
    }
    __syncthreads();
    float mfin[2][4];
    #pragma unroll
    for (int i = 0; i < 2; ++i)
        #pragma unroll
        for (int r2 = 0; r2 < 4; ++r2)
            mfin[i][r2] = rowred[i * 16 + rb + r2];
    __syncthreads();   // everyone read rowred(max) before it is overwritten

    float sm[2][4] = {{0.f, 0.f, 0.f, 0.f}, {0.f, 0.f, 0.f, 0.f}};
    #pragma unroll
    for (int i = 0; i < 2; ++i)
        #pragma unroll
        for (int j = 0; j < 16; ++j)
            #pragma unroll
            for (int r2 = 0; r2 < 4; ++r2) {
                const float p = expf(acc[i][j][r2] - mfin[i][r2]);
                acc[i][j][r2] = p;
                sm[i][r2] += p;
            }
    #pragma unroll
    for (int o = 1; o < 16; o <<= 1)
        #pragma unroll
        for (int i = 0; i < 2; ++i)
            #pragma unroll
            for (int r2 = 0; r2 < 4; ++r2)
                sm[i][r2] += __shfl_xor(sm[i][r2], o);
    if (fr == 0) {
        #pragma unroll
        for (int i = 0; i < 2; ++i)
            #pragma unroll
            for (int r2 = 0; r2 < 4; ++r2)
                red[w * 32 + i * 16 + rb + r2] = sm[i][r2];
    }
    __syncthreads();
    if (tid < 32) {
        float s = red[tid];
        #pragma unroll
        for (int ww = 1; ww < 8; ++ww) s += red[ww * 32 + tid];
        rowred[tid] = 1.0f / s;
    }
    __syncthreads();
    float inv[2][4];
    #pragma unroll
    for (int i = 0; i < 2; ++i)
        #pragma unroll
        for (int r2 = 0; r2 < 4; ++r2)
            inv[i][r2] = rowred[i * 16 + rb + r2];

    // ---- write attn fp32 + attnb bf16 ----
    const size_t tbase = (size_t)b * TT + (size_t)tb * 32;
    #pragma unroll
    for (int i = 0; i < 2; ++i)
        #pragma unroll
        for (int r2 = 0; r2 < 4; ++r2) {
            const size_t rowoff = (tbase + i * 16 + rb + r2) * SS;
            #pragma unroll
            for (int j = 0; j < 16; ++j) {
                const int col = n0w + (j >> 2) * 64 + (j & 3) * 16 + fr;
                const float p = acc[i][j][r2] * inv[i][r2];
                attn[rowoff + col]  = p;
                attnb[rowoff + col] = f2bf(p);
            }
        }
}

// Partial t-sums of attn: part[b][c][s] = sum_{t in chunk c} attnb[b][t][s].
__global__ __launch_bounds__(256) void k_xmean_part(const unsigned short* __restrict__ attnb,
                                                    float* __restrict__ part)
{
    const int c = blockIdx.x, b = blockIdx.y;
    const unsigned short* p = attnb + ((size_t)b * TT + (size_t)c * (TT / XCH)) * SS
                              + threadIdx.x * 8;
    float acc[8] = {0.f, 0.f, 0.f, 0.f, 0.f, 0.f, 0.f, 0.f};
    #pragma unroll 8
    for (int t = 0; t < TT / XCH; ++t) {
        union { unsigned short u[8]; uint4 v4; } ld;
        ld.v4 = *reinterpret_cast<const uint4*>(p + (size_t)t * SS);
        #pragma unroll
        for (int i = 0; i < 8; ++i) acc[i] += bf2f(ld.u[i]);
    }
    float* o = part + ((size_t)b * XCH + c) * SS + threadIdx.x * 8;
    #pragma unroll
    for (int i = 0; i < 8; ++i) o[i] = acc[i];
}

// ns[b,n,:] = enc_values[b, n*STRIDE, :]/||.||;  aa[b,n] from partials. Zeroes klp.
__global__ __launch_bounds__(256) void k_ns(const float* __restrict__ ev,
                                            const float* __restrict__ part,
                                            float* __restrict__ ns, float* __restrict__ aa,
                                            float* __restrict__ klp)
{
    const int n = blockIdx.x, b = blockIdx.y;
    const int tid = threadIdx.x;
    if (n == 0 && b == 0 && tid == 0) klp[0] = 0.0f;
    const float* rowp = ev + ((size_t)b * SS + (size_t)n * STRIDE_) * EE;
    const float v = rowp[tid];
    __shared__ float w[4];
    float r = wave_sum(v * v);
    if ((tid & 63) == 0) w[tid >> 6] = r;
    float pv = (tid < XCH) ? part[((size_t)b * XCH + tid) * SS + n * STRIDE_] : 0.f;
    float psum = wave_sum(pv);
    __syncthreads();
    const float nrm = sqrtf(w[0] + w[1] + w[2] + w[3]);
    ns[((size_t)b * NSUB + n) * EE + tid] = v / nrm;
    if (tid == 0) aa[b * NSUB + n] = psum * (1.0f / TT);
}

// L[b,i,j] = (aa_i*aa_j) * dot(ns_i, ns_j).  grid (N, B), 128 thr
__global__ __launch_bounds__(128) void k_L(const float* __restrict__ ns,
                                           const float* __restrict__ aa,
                                           float* __restrict__ Lm)
{
    const int i = blockIdx.x, b = blockIdx.y;
    const int tid = threadIdx.x;
    __shared__ float nsi[EE];
    nsi[tid]       = ns[((size_t)b * NSUB + i) * EE + tid];
    nsi[tid + 128] = ns[((size_t)b * NSUB + i) * EE + tid + 128];
    __syncthreads();
    const float ai = aa[b * NSUB + i];
    for (int j = tid; j < NSUB; j += 128) {
        const float* rj = ns + ((size_t)b * NSUB + j) * EE;
        float d = 0.f;
        #pragma unroll 4
        for (int e = 0; e < EE; ++e) d += nsi[e] * rj[e];
        Lm[((size_t)b * NSUB + i) * NSUB + j] = d * ai * aa[b * NSUB + j];
    }
}

// Greedy MAP DPP (Cholesky) + dist + KL — one block per batch, 256 thr.
// Cm padded to stride 21 (kills 4-way LDS bank conflict of stride-20 rows).
__global__ __launch_bounds__(256) void k_bfgm_kl(const float* __restrict__ Lm,
                                                 const float* __restrict__ part,
                                                 float* __restrict__ outkl)
{
    const int b = blockIdx.x;
    const int tid = threadIdx.x;
    const float* L = Lm + (size_t)b * NSUB * NSUB;
    __shared__ float D[128], mask[128], Cm[128 * 21], cj[MAXS], musS[MAXS];
    __shared__ float rv[4];
    __shared__ int   ri[4];
    __shared__ int   Jsh;
    __shared__ float w[4];
    const bool half = tid < 128;
    const bool act  = tid < NSUB;
    if (half) {
        D[tid]    = act ? L[(size_t)tid * NSUB + tid] : 0.0f;
        mask[tid] = act ? 1.0f : 0.0f;
        #pragma unroll
        for (int k = 0; k < MAXS; ++k) Cm[tid * 21 + k] = 0.0f;
    }
    __syncthreads();

    auto argmax_step = [&](int t) {
        float key = act ? logf(D[tid] * mask[tid]) : -INFINITY;
        if (isnan(key)) key = INFINITY;   // numpy argmax: NaN wins
        float v = key; int idx = tid;
        #pragma unroll
        for (int o = 32; o; o >>= 1) {
            float ov = __shfl_down(v, o); int oi = __shfl_down(idx, o);
            if (ov > v || (ov == v && oi < idx)) { v = ov; idx = oi; }
        }
        if ((tid & 63) == 0) { rv[tid >> 6] = v; ri[tid >> 6] = idx; }
        __syncthreads();
        if (tid == 0) {
            float bv = rv[0]; int bi = ri[0];
            #pragma unroll
            for (int q2 = 1; q2 < 4; ++q2)
                if (rv[q2] > bv || (rv[q2] == bv && ri[q2] < bi)) { bv = rv[q2]; bi = ri[q2]; }
            Jsh = bi; mask[bi] = 0.0f; musS[t] = (float)bi;
        }
        __syncthreads();
    };

    argmax_step(0);
    for (int t = 1; t < MAXS; ++t) {
        if (tid < MAXS) cj[tid] = Cm[Jsh * 21 + tid];
        __syncthreads();
        const int J = Jsh;
        const float dj = D[J];
        float e = 0.0f;
        if (act) {
            const float Ljn = L[(size_t)J * NSUB + tid];
            float cd = 0.f;
            #pragma unroll
            for (int k = 0; k < MAXS; ++k) cd += Cm[tid * 21 + k] * cj[k];
            e = (Ljn - cd) / dj * mask[tid];
        }
        if (half) { Cm[tid * 21 + t] = e; D[tid] -= e * e; }
        __syncthreads();
        argmax_step(t);
    }

    // ---- dist softmax + KL (all 256 threads) ----
    float xm[8];
    #pragma unroll
    for (int i = 0; i < 8; ++i) {
        float s = 0.f;
        #pragma unroll 8
        for (int c2 = 0; c2 < XCH; ++c2)
            s += part[((size_t)b * XCH + c2) * SS + tid + (i << 8)];
        xm[i] = s * (1.0f / TT);
    }
    float g[8];
    float mx = -INFINITY;
    #pragma unroll
    for (int i = 0; i < 8; ++i) {
        const float s = (float)(tid + (i << 8));
        float acc = 0.f;
        #pragma unroll
        for (int m = 0; m < MAXS; ++m) { const float z = s - musS[m]; acc += expf(-(z * z) * INV2S2); }
        g[i] = acc * GNORM;
        mx = fmaxf(mx, g[i]);
    }
    float wm = wave_max(mx);
    if ((tid & 63) == 0) w[tid >> 6] = wm;
    __syncthreads();
    const float m = fmaxf(fmaxf(w[0], w[1]), fmaxf(w[2], w[3]));
    float sum = 0.f;
    #pragma unroll
    for (int i = 0; i < 8; ++i) { g[i] = expf(g[i] - m); sum += g[i]; }
    __syncthreads();
    float wsv = wave_sum(sum);
    if ((tid & 63) == 0) w[tid >> 6] = wsv;
    __syncthreads();
    const float inv = 1.0f / (w[0] + w[1] + w[2] + w[3]);
    float acc2 = 0.f;
    #pragma unroll
    for (int i = 0; i < 8; ++i)
        acc2 += xm[i] * (logf(xm[i]) - g[i] * inv);
    __syncthreads();
    float wp = wave_sum(acc2);
    if ((tid & 63) == 0) w[tid >> 6] = wp;
    __syncthreads();
    if (tid == 0) atomicAdd(outkl, -(w[0] + w[1] + w[2] + w[3]));
}

extern "C" void kernel_launch(void* const* d_in, const int* in_sizes, int n_in,
                              void* d_out, int out_size, void* d_ws, size_t ws_size,
                              hipStream_t stream)
{
    const float* x     = (const float*)d_in[0];   // (B,T,C)
    const float* te    = (const float*)d_in[1];   // (B,T,E)
    const float* keys  = (const float*)d_in[2];   // (B,E,S)
    const float* vals  = (const float*)d_in[3];   // (B,S,E)
    const float* W_in  = (const float*)d_in[4];   // (E,C)
    const float* b_in  = (const float*)d_in[5];   // (E)
    const float* W_out = (const float*)d_in[6];   // (C,E)
    const float* b_out = (const float*)d_in[7];   // (C)

    float* outp = (float*)d_out;                       // (B,T,C)
    float* attn = outp + (size_t)BB * TT * CC;         // (B,T,S) fp32
    float* klp  = attn + (size_t)BB * TT * SS;         // scalar

    // workspace
    unsigned short* X       = (unsigned short*)d_ws;
    unsigned short* x_bf    = X;                                       // B*T*C
    unsigned short* Win_bf  = x_bf   + (size_t)BB * TT * CC;           // E*C
    unsigned short* Wout_bf = Win_bf + (size_t)EE * CC;                // C*E
    unsigned short* h_bf    = Wout_bf+ (size_t)CC * EE;                // B*T*E
    unsigned short* keysT   = h_bf   + (size_t)BB * TT * EE;           // B*S*E
    unsigned short* valsT   = keysT  + (size_t)BB * SS * EE;           // B*E*S
    unsigned short* attnb   = valsT  + (size_t)BB * EE * SS;           // B*T*S
    unsigned short* mid_bf  = attnb  + (size_t)BB * TT * SS;           // B*T*E
    float* fws   = (float*)(mid_bf + (size_t)BB * TT * EE + 8);
    float* part  = fws;                                  // (B,XCH,S)
    float* ns    = part  + (size_t)BB * XCH * SS;        // (B,N,E)
    float* aa    = ns    + (size_t)BB * NSUB * EE;       // (B,N)
    float* Lm    = aa    + (size_t)BB * NSUB;            // (B,N,N)

    // casts (x, W_in, W_out in one launch)
    {
        const int na = BB * TT * CC / 4, nb = EE * CC / 4, nc = CC * EE / 4;
        const int blocks = (na + nb + nc + 255) / 256;
        k_cast3<<<blocks, 256, 0, stream>>>(x, x_bf, na, W_in, Win_bf, nb, W_out, Wout_bf, nc);
    }
    // 1) h_bf = bf16((x @ W_in^T + b_in + te) * sqrt(.5))   [64x64, 1024 blocks]
    k_gemm<64, 64, 2><<<dim3(256, 4, 1), 256, 0, stream>>>(
        x_bf, Win_bf, b_in, te, nullptr, h_bf, BB * TT, CC, CC, 1.0f);
    // 2) keysT[b,s,e] = keys[b,e,s] (bf16)
    k_transpose_bf16<<<dim3(4, 32, BB), 256, 0, stream>>>(keys, keysT, EE, SS);
    // 3) fused scores + softmax -> attn fp32 + attnb bf16   [512 blocks]
    k_qk_softmax<<<dim3(TT / 32, BB), 512, 0, stream>>>(h_bf, keysT, attn, attnb);
    // 4) valsT[b,e,s] = vals[b,s,e] (bf16)
    k_transpose_bf16<<<dim3(32, 4, BB), 256, 0, stream>>>(vals, valsT, SS, EE);
    // 5) x_mean partials from bf16 attn   [512 blocks]
    k_xmean_part<<<dim3(XCH, BB), 256, 0, stream>>>(attnb, part);
    // 6) DPP chain (k_ns zeroes klp for the k_bfgm_kl atomics)
    k_ns<<<dim3(NSUB, BB), 256, 0, stream>>>(vals, part, ns, aa, klp);
    k_L<<<dim3(NSUB, BB), 128, 0, stream>>>(ns, aa, Lm);
    k_bfgm_kl<<<BB, 256, 0, stream>>>(Lm, part, klp);
    // 7) mid_bf = bf16((attn @ enc_values) * sqrt(S))   [64x128, 512 blocks]
    k_gemm<64, 128, 3><<<dim3(16, 2, BB), 256, 0, stream>>>(
        attnb, valsT, nullptr, nullptr, nullptr, mid_bf, TT, EE, SS, SQRT_S);
    // 8) out = (mid @ W_out^T + b_out + x) * sqrt(.5)   [64x64, 1024 blocks]
    k_gemm<64, 64, 1><<<dim3(256, 4, 1), 256, 0, stream>>>(
        mid_bf, Wout_bf, b_out, x, outp, nullptr, BB * TT, CC, CC, 1.0f);
}

// Round 7
// 460.133 us; speedup vs baseline: 1.0689x; 1.0689x over previous
//
#include <hip/hip_runtime.h>
#include <math.h>

#define BB 16
#define TT 1024
#define SS 2048
#define CC 256
#define EE 256
#define NSUB 103        // (SS-1)/STRIDE + 1
#define MAXS 20
#define STRIDE_ 20
#define XCH 32          // t-chunks for xmean partials (TT/XCH = 32 rows each)

static constexpr float RSQRT2  = 0.70710678118654752440f;   // sqrt(0.5)
static constexpr float SQRT_S  = 45.25483399593904f;        // s*sqrt(1/s) = sqrt(2048)
static constexpr float GNORM   = 0.13298076013381093f;      // 1/(sqrt(2*pi)*3)
static constexpr float INV2S2  = 0.055555555555555555f;     // 1/(2*sigma^2)

typedef __attribute__((ext_vector_type(8))) __bf16 bf16x8;
typedef __attribute__((ext_vector_type(4))) float  f32x4;

__device__ __forceinline__ float wave_sum(float v) {
    #pragma unroll
    for (int o = 32; o; o >>= 1) v += __shfl_down(v, o);
    return v;
}
__device__ __forceinline__ float wave_max(float v) {
    #pragma unroll
    for (int o = 32; o; o >>= 1) v = fmaxf(v, __shfl_down(v, o));
    return v;
}
__device__ __forceinline__ unsigned short f2bf(float f) {   // RNE
    unsigned int u = __float_as_uint(f);
    u = (u + 0x7FFFu + ((u >> 16) & 1u)) >> 16;
    return (unsigned short)u;
}
__device__ __forceinline__ float bf2f(unsigned short s) {
    return __uint_as_float(((unsigned int)s) << 16);
}

#define GLD_LDS16(g, l) __builtin_amdgcn_global_load_lds(                      \
    (const __attribute__((address_space(1))) void*)(g),                        \
    (__attribute__((address_space(3))) void*)(l), 16, 0, 0)

// fp32 -> bf16 cast over three disjoint buffers in one launch.
__global__ __launch_bounds__(256) void k_cast3(
    const float* __restrict__ a,  unsigned short* __restrict__ oa, int na,
    const float* __restrict__ b2, unsigned short* __restrict__ ob, int nb,
    const float* __restrict__ c2, unsigned short* __restrict__ oc, int nc)
{
    int i = blockIdx.x * 256 + threadIdx.x;
    const float* in; unsigned short* out;
    if (i < na)                { in = a;  out = oa; }
    else if (i < na + nb)      { in = b2; out = ob; i -= na; }
    else if (i < na + nb + nc) { in = c2; out = oc; i -= na + nb; }
    else return;
    const float4 v = reinterpret_cast<const float4*>(in)[i];
    union { unsigned short u[4]; unsigned long long v8; } pk;
    pk.u[0] = f2bf(v.x); pk.u[1] = f2bf(v.y);
    pk.u[2] = f2bf(v.z); pk.u[3] = f2bf(v.w);
    reinterpret_cast<unsigned long long*>(out)[i] = pk.v8;
}

// Both input transposes (keys and vals) in ONE launch of 4096 blocks.
// fp32 [Bz][R][Cc] -> bf16 [Bz][Cc][R].
// id < 2048: keys  (R=EE=256,  Cc=SS=2048), grid decode (4, 32, 16)
// id >=2048: vals  (R=SS=2048, Cc=EE=256),  grid decode (32, 4, 16)
__global__ __launch_bounds__(256) void k_transpose2(
    const float* __restrict__ keys, unsigned short* __restrict__ keysT,
    const float* __restrict__ vals, unsigned short* __restrict__ valsT)
{
    __shared__ float t[64][65];
    const int id = blockIdx.x;
    const float* in; unsigned short* out;
    int R, Cc, bx, by, b;
    if (id < 2048) {
        in = keys; out = keysT; R = EE; Cc = SS;
        bx = id & 3; by = (id >> 2) & 31; b = id >> 7;
    } else {
        const int id2 = id - 2048;
        in = vals; out = valsT; R = SS; Cc = EE;
        bx = id2 & 31; by = (id2 >> 5) & 3; b = id2 >> 7;
    }
    const int r0 = bx * 64, c0 = by * 64;
    const float* ip = in + (size_t)b * R * Cc;
    unsigned short* op = out + (size_t)b * R * Cc;
    const int tx = threadIdx.x & 63, ty = threadIdx.x >> 6;  // ty in [0,4)
    #pragma unroll
    for (int i = 0; i < 16; ++i)
        t[ty + 4 * i][tx] = ip[(size_t)(r0 + ty + 4 * i) * Cc + c0 + tx];
    __syncthreads();
    #pragma unroll
    for (int i = 0; i < 16; ++i)
        op[(size_t)(c0 + ty + 4 * i) * R + r0 + tx] = f2bf(t[tx][ty + 4 * i]);
}

// ---------------------------------------------------------------------------
// Unified bf16 MFMA GEMM (R5-proven): BK=64, XOR-swizzled LDS (pre-swizzled
// global source column, linear global_load_lds dest; reads apply the same
// XOR), XCD-chunked bijective blockIdx swizzle. 4 waves, 2x2 wave grid.
// MODE 0: Of = acc*scale
// MODE 1: Of = (acc + bias[n] + add[m,n])*RSQRT2
// MODE 2: Ob = bf16((acc + bias[n] + add[m,n])*RSQRT2)
// MODE 3: Ob = bf16(acc*scale)
// ---------------------------------------------------------------------------
template<int BM, int BN, int MODE>
__global__ __launch_bounds__(256) void k_gemm(
    const unsigned short* __restrict__ Abase,
    const unsigned short* __restrict__ Btbase,
    const float* __restrict__ bias, const float* __restrict__ add,
    float* __restrict__ Obase, unsigned short* __restrict__ Obbase,
    int M, int Nn, int K, float scale)
{
    constexpr int BK = 64;
    constexpr int AR = BM / 32;
    constexpr int BR = BN / 32;
    constexpr int WM = BM / 2, WN = BN / 2;
    constexpr int MI = WM / 16, NJ = WN / 16;

    __shared__ unsigned short As[BM * BK];
    __shared__ unsigned short Bs[BN * BK];

    const int nwg = gridDim.x * gridDim.y * gridDim.z;
    int l = blockIdx.x + gridDim.x * (blockIdx.y + gridDim.y * blockIdx.z);
    if ((nwg & 7) == 0) l = (l & 7) * (nwg >> 3) + (l >> 3);
    const int bx = l % gridDim.x; l /= gridDim.x;
    const int by = l % gridDim.y;
    const int b  = l / gridDim.y;

    const int m0 = bx * BM;
    const int n0 = by * BN;
    const unsigned short* A  = Abase  + (size_t)b * M  * K;
    const unsigned short* Bt = Btbase + (size_t)b * Nn * K;

    const int tid  = threadIdx.x;
    const int w    = tid >> 6;
    const int lane = tid & 63;
    const int wm   = w & 1, wn = w >> 1;

    const int sr  = tid >> 3;
    const int skb = ((tid & 7) << 4) ^ ((sr & 7) << 4);
    const unsigned short* ga[AR];
    const unsigned short* gb[BR];
    #pragma unroll
    for (int p = 0; p < AR; ++p)
        ga[p] = A + (size_t)(m0 + p * 32 + sr) * K + (skb >> 1);
    #pragma unroll
    for (int p = 0; p < BR; ++p)
        gb[p] = Bt + (size_t)(n0 + p * 32 + sr) * K + (skb >> 1);

    const int fr = lane & 15;
    const int qb = (lane >> 4) << 4;

    f32x4 acc[MI][NJ];
    #pragma unroll
    for (int i = 0; i < MI; ++i)
        #pragma unroll
        for (int j = 0; j < NJ; ++j)
            acc[i][j] = (f32x4){0.f, 0.f, 0.f, 0.f};

    for (int k0 = 0; k0 < K; k0 += BK) {
        #pragma unroll
        for (int p = 0; p < AR; ++p) GLD_LDS16(ga[p], As + p * 2048 + w * 512);
        #pragma unroll
        for (int p = 0; p < BR; ++p) GLD_LDS16(gb[p], Bs + p * 2048 + w * 512);
        #pragma unroll
        for (int p = 0; p < AR; ++p) ga[p] += BK;
        #pragma unroll
        for (int p = 0; p < BR; ++p) gb[p] += BK;
        __syncthreads();
        #pragma unroll
        for (int c = 0; c < 2; ++c) {
            bf16x8 af[MI], bf[NJ];
            #pragma unroll
            for (int i = 0; i < MI; ++i) {
                const int row = wm * WM + i * 16 + fr;
                const int byt = row * 128 + ((c * 64 + qb) ^ ((row & 7) << 4));
                af[i] = *reinterpret_cast<const bf16x8*>(
                            reinterpret_cast<const char*>(As) + byt);
            }
            #pragma unroll
            for (int j = 0; j < NJ; ++j) {
                const int row = wn * WN + j * 16 + fr;
                const int byt = row * 128 + ((c * 64 + qb) ^ ((row & 7) << 4));
                bf[j] = *reinterpret_cast<const bf16x8*>(
                            reinterpret_cast<const char*>(Bs) + byt);
            }
            #pragma unroll
            for (int i = 0; i < MI; ++i)
                #pragma unroll
                for (int j = 0; j < NJ; ++j)
                    acc[i][j] = __builtin_amdgcn_mfma_f32_16x16x32_bf16(af[i], bf[j], acc[i][j], 0, 0, 0);
        }
        __syncthreads();
    }

    float* Of = (MODE == 0 || MODE == 1) ? Obase + (size_t)b * M * Nn : nullptr;
    unsigned short* Ob = (MODE == 2 || MODE == 3) ? Obbase + (size_t)b * M * Nn : nullptr;
    const int rb = (lane >> 4) * 4;
    #pragma unroll
    for (int i = 0; i < MI; ++i)
        #pragma unroll
        for (int j = 0; j < NJ; ++j) {
            const int n = n0 + wn * WN + j * 16 + fr;
            #pragma unroll
            for (int r2 = 0; r2 < 4; ++r2) {
                const int m = m0 + wm * WM + i * 16 + rb + r2;
                const size_t idx = (size_t)m * Nn + n;
                if (MODE == 0) {
                    Of[idx] = acc[i][j][r2] * scale;
                } else if (MODE == 1) {
                    Of[idx] = (acc[i][j][r2] + bias[n] + add[idx]) * RSQRT2;
                } else if (MODE == 2) {
                    Ob[idx] = f2bf((acc[i][j][r2] + bias[n] + add[idx]) * RSQRT2);
                } else {
                    Ob[idx] = f2bf(acc[i][j][r2] * scale);
                }
            }
        }
}

// Row softmax over S=2048, ONE WAVE PER ROW (4 rows per 256-thr block).
// Zero barriers, zero LDS: reductions are 6-step __shfl_xor butterflies.
// Input: bf16 scores in attnb; output: fp32 attn + bf16 attnb in place.
// grid BB*TT/4 = 4096 blocks.
__global__ __launch_bounds__(256) void k_softmax(float* __restrict__ attn,
                                                 unsigned short* __restrict__ attnb)
{
    const int row  = blockIdx.x * 4 + (threadIdx.x >> 6);
    const int lane = threadIdx.x & 63;
    float* p = attn + (size_t)row * SS;
    unsigned short* pb = attnb + (size_t)row * SS;

    float v[32];
    #pragma unroll
    for (int s = 0; s < 4; ++s) {
        union { unsigned short u[8]; uint4 q; } ld;
        ld.q = *reinterpret_cast<const uint4*>(&pb[s * 512 + lane * 8]);
        #pragma unroll
        for (int i = 0; i < 8; ++i) v[s * 8 + i] = bf2f(ld.u[i]);
    }
    float mx = v[0];
    #pragma unroll
    for (int i = 1; i < 32; ++i) mx = fmaxf(mx, v[i]);
    #pragma unroll
    for (int o = 32; o; o >>= 1) mx = fmaxf(mx, __shfl_xor(mx, o));
    float s = 0.f;
    #pragma unroll
    for (int i = 0; i < 32; ++i) { v[i] = expf(v[i] - mx); s += v[i]; }
    #pragma unroll
    for (int o = 32; o; o >>= 1) s += __shfl_xor(s, o);
    const float inv = 1.0f / s;
    #pragma unroll
    for (int seg = 0; seg < 4; ++seg) {
        float4 o0, o1;
        o0.x = v[seg * 8 + 0] * inv; o0.y = v[seg * 8 + 1] * inv;
        o0.z = v[seg * 8 + 2] * inv; o0.w = v[seg * 8 + 3] * inv;
        o1.x = v[seg * 8 + 4] * inv; o1.y = v[seg * 8 + 5] * inv;
        o1.z = v[seg * 8 + 6] * inv; o1.w = v[seg * 8 + 7] * inv;
        *reinterpret_cast<float4*>(&p[seg * 512 + lane * 8])     = o0;
        *reinterpret_cast<float4*>(&p[seg * 512 + lane * 8 + 4]) = o1;
        union { unsigned short u[8]; uint4 q; } pk;
        pk.u[0] = f2bf(o0.x); pk.u[1] = f2bf(o0.y); pk.u[2] = f2bf(o0.z); pk.u[3] = f2bf(o0.w);
        pk.u[4] = f2bf(o1.x); pk.u[5] = f2bf(o1.y); pk.u[6] = f2bf(o1.z); pk.u[7] = f2bf(o1.w);
        *reinterpret_cast<uint4*>(&pb[seg * 512 + lane * 8]) = pk.q;
    }
}

// Partial t-sums of attn: part[b][c][s] = sum_{t in chunk c} attnb[b][t][s].
__global__ __launch_bounds__(256) void k_xmean_part(const unsigned short* __restrict__ attnb,
                                                    float* __restrict__ part)
{
    const int c = blockIdx.x, b = blockIdx.y;
    const unsigned short* p = attnb + ((size_t)b * TT + (size_t)c * (TT / XCH)) * SS
                              + threadIdx.x * 8;
    float acc[8] = {0.f, 0.f, 0.f, 0.f, 0.f, 0.f, 0.f, 0.f};
    #pragma unroll 8
    for (int t = 0; t < TT / XCH; ++t) {
        union { unsigned short u[8]; uint4 v4; } ld;
        ld.v4 = *reinterpret_cast<const uint4*>(p + (size_t)t * SS);
        #pragma unroll
        for (int i = 0; i < 8; ++i) acc[i] += bf2f(ld.u[i]);
    }
    float* o = part + ((size_t)b * XCH + c) * SS + threadIdx.x * 8;
    #pragma unroll
    for (int i = 0; i < 8; ++i) o[i] = acc[i];
}

// ns[b,n,:] = enc_values[b, n*STRIDE, :]/||.||;  aa[b,n] from partials. Zeroes klp.
__global__ __launch_bounds__(256) void k_ns(const float* __restrict__ ev,
                                            const float* __restrict__ part,
                                            float* __restrict__ ns, float* __restrict__ aa,
                                            float* __restrict__ klp)
{
    const int n = blockIdx.x, b = blockIdx.y;
    const int tid = threadIdx.x;
    if (n == 0 && b == 0 && tid == 0) klp[0] = 0.0f;
    const float* rowp = ev + ((size_t)b * SS + (size_t)n * STRIDE_) * EE;
    const float v = rowp[tid];
    __shared__ float w[4];
    float r = wave_sum(v * v);
    if ((tid & 63) == 0) w[tid >> 6] = r;
    float pv = (tid < XCH) ? part[((size_t)b * XCH + tid) * SS + n * STRIDE_] : 0.f;
    float psum = wave_sum(pv);
    __syncthreads();
    const float nrm = sqrtf(w[0] + w[1] + w[2] + w[3]);
    ns[((size_t)b * NSUB + n) * EE + tid] = v / nrm;
    if (tid == 0) aa[b * NSUB + n] = psum * (1.0f / TT);
}

// L[b,i,j] = (aa_i*aa_j) * dot(ns_i, ns_j).  grid (N, B), 128 thr
__global__ __launch_bounds__(128) void k_L(const float* __restrict__ ns,
                                           const float* __restrict__ aa,
                                           float* __restrict__ Lm)
{
    const int i = blockIdx.x, b = blockIdx.y;
    const int tid = threadIdx.x;
    __shared__ float nsi[EE];
    nsi[tid]       = ns[((size_t)b * NSUB + i) * EE + tid];
    nsi[tid + 128] = ns[((size_t)b * NSUB + i) * EE + tid + 128];
    __syncthreads();
    const float ai = aa[b * NSUB + i];
    for (int j = tid; j < NSUB; j += 128) {
        const float* rj = ns + ((size_t)b * NSUB + j) * EE;
        float d = 0.f;
        #pragma unroll 4
        for (int e = 0; e < EE; ++e) d += nsi[e] * rj[e];
        Lm[((size_t)b * NSUB + i) * NSUB + j] = d * ai * aa[b * NSUB + j];
    }
}

// Greedy MAP DPP (Cholesky) + dist + KL — one block per batch, 256 thr.
// Cm padded to stride 21 (kills 4-way LDS bank conflict of stride-20 rows).
__global__ __launch_bounds__(256) void k_bfgm_kl(const float* __restrict__ Lm,
                                                 const float* __restrict__ part,
                                                 float* __restrict__ outkl)
{
    const int b = blockIdx.x;
    const int tid = threadIdx.x;
    const float* L = Lm + (size_t)b * NSUB * NSUB;
    __shared__ float D[128], mask[128], Cm[128 * 21], cj[MAXS], musS[MAXS];
    __shared__ float rv[4];
    __shared__ int   ri[4];
    __shared__ int   Jsh;
    __shared__ float w[4];
    const bool half = tid < 128;
    const bool act  = tid < NSUB;
    if (half) {
        D[tid]    = act ? L[(size_t)tid * NSUB + tid] : 0.0f;
        mask[tid] = act ? 1.0f : 0.0f;
        #pragma unroll
        for (int k = 0; k < MAXS; ++k) Cm[tid * 21 + k] = 0.0f;
    }
    __syncthreads();

    auto argmax_step = [&](int t) {
        float key = act ? logf(D[tid] * mask[tid]) : -INFINITY;
        if (isnan(key)) key = INFINITY;   // numpy argmax: NaN wins
        float v = key; int idx = tid;
        #pragma unroll
        for (int o = 32; o; o >>= 1) {
            float ov = __shfl_down(v, o); int oi = __shfl_down(idx, o);
            if (ov > v || (ov == v && oi < idx)) { v = ov; idx = oi; }
        }
        if ((tid & 63) == 0) { rv[tid >> 6] = v; ri[tid >> 6] = idx; }
        __syncthreads();
        if (tid == 0) {
            float bv = rv[0]; int bi = ri[0];
            #pragma unroll
            for (int q2 = 1; q2 < 4; ++q2)
                if (rv[q2] > bv || (rv[q2] == bv && ri[q2] < bi)) { bv = rv[q2]; bi = ri[q2]; }
            Jsh = bi; mask[bi] = 0.0f; musS[t] = (float)bi;
        }
        __syncthreads();
    };

    argmax_step(0);
    for (int t = 1; t < MAXS; ++t) {
        if (tid < MAXS) cj[tid] = Cm[Jsh * 21 + tid];
        __syncthreads();
        const int J = Jsh;
        const float dj = D[J];
        float e = 0.0f;
        if (act) {
            const float Ljn = L[(size_t)J * NSUB + tid];
            float cd = 0.f;
            #pragma unroll
            for (int k = 0; k < MAXS; ++k) cd += Cm[tid * 21 + k] * cj[k];
            e = (Ljn - cd) / dj * mask[tid];
        }
        if (half) { Cm[tid * 21 + t] = e; D[tid] -= e * e; }
        __syncthreads();
        argmax_step(t);
    }

    // ---- dist softmax + KL (all 256 threads) ----
    float xm[8];
    #pragma unroll
    for (int i = 0; i < 8; ++i) {
        float s = 0.f;
        #pragma unroll 8
        for (int c2 = 0; c2 < XCH; ++c2)
            s += part[((size_t)b * XCH + c2) * SS + tid + (i << 8)];
        xm[i] = s * (1.0f / TT);
    }
    float g[8];
    float mx = -INFINITY;
    #pragma unroll
    for (int i = 0; i < 8; ++i) {
        const float s = (float)(tid + (i << 8));
        float acc = 0.f;
        #pragma unroll
        for (int m = 0; m < MAXS; ++m) { const float z = s - musS[m]; acc += expf(-(z * z) * INV2S2); }
        g[i] = acc * GNORM;
        mx = fmaxf(mx, g[i]);
    }
    float wm = wave_max(mx);
    if ((tid & 63) == 0) w[tid >> 6] = wm;
    __syncthreads();
    const float m = fmaxf(fmaxf(w[0], w[1]), fmaxf(w[2], w[3]));
    float sum = 0.f;
    #pragma unroll
    for (int i = 0; i < 8; ++i) { g[i] = expf(g[i] - m); sum += g[i]; }
    __syncthreads();
    float wsv = wave_sum(sum);
    if ((tid & 63) == 0) w[tid >> 6] = wsv;
    __syncthreads();
    const float inv = 1.0f / (w[0] + w[1] + w[2] + w[3]);
    float acc2 = 0.f;
    #pragma unroll
    for (int i = 0; i < 8; ++i)
        acc2 += xm[i] * (logf(xm[i]) - g[i] * inv);
    __syncthreads();
    float wp = wave_sum(acc2);
    if ((tid & 63) == 0) w[tid >> 6] = wp;
    __syncthreads();
    if (tid == 0) atomicAdd(outkl, -(w[0] + w[1] + w[2] + w[3]));
}

extern "C" void kernel_launch(void* const* d_in, const int* in_sizes, int n_in,
                              void* d_out, int out_size, void* d_ws, size_t ws_size,
                              hipStream_t stream)
{
    const float* x     = (const float*)d_in[0];   // (B,T,C)
    const float* te    = (const float*)d_in[1];   // (B,T,E)
    const float* keys  = (const float*)d_in[2];   // (B,E,S)
    const float* vals  = (const float*)d_in[3];   // (B,S,E)
    const float* W_in  = (const float*)d_in[4];   // (E,C)
    const float* b_in  = (const float*)d_in[5];   // (E)
    const float* W_out = (const float*)d_in[6];   // (C,E)
    const float* b_out = (const float*)d_in[7];   // (C)

    float* outp = (float*)d_out;                       // (B,T,C)
    float* attn = outp + (size_t)BB * TT * CC;         // (B,T,S) fp32
    float* klp  = attn + (size_t)BB * TT * SS;         // scalar

    // workspace
    unsigned short* X       = (unsigned short*)d_ws;
    unsigned short* x_bf    = X;                                       // B*T*C
    unsigned short* Win_bf  = x_bf   + (size_t)BB * TT * CC;           // E*C
    unsigned short* Wout_bf = Win_bf + (size_t)EE * CC;                // C*E
    unsigned short* h_bf    = Wout_bf+ (size_t)CC * EE;                // B*T*E
    unsigned short* keysT   = h_bf   + (size_t)BB * TT * EE;           // B*S*E
    unsigned short* valsT   = keysT  + (size_t)BB * SS * EE;           // B*E*S
    unsigned short* attnb   = valsT  + (size_t)BB * EE * SS;           // B*T*S (scores, then attn)
    unsigned short* mid_bf  = attnb  + (size_t)BB * TT * SS;           // B*T*E
    float* fws   = (float*)(mid_bf + (size_t)BB * TT * EE + 8);
    float* part  = fws;                                  // (B,XCH,S)
    float* ns    = part  + (size_t)BB * XCH * SS;        // (B,N,E)
    float* aa    = ns    + (size_t)BB * NSUB * EE;       // (B,N)
    float* Lm    = aa    + (size_t)BB * NSUB;            // (B,N,N)

    // casts (x, W_in, W_out in one launch)
    {
        const int na = BB * TT * CC / 4, nb = EE * CC / 4, nc = CC * EE / 4;
        const int blocks = (na + nb + nc + 255) / 256;
        k_cast3<<<blocks, 256, 0, stream>>>(x, x_bf, na, W_in, Win_bf, nb, W_out, Wout_bf, nc);
    }
    // 1) h_bf = bf16((x @ W_in^T + b_in + te) * sqrt(.5))   [64x64, 1024 blocks]
    k_gemm<64, 64, 2><<<dim3(256, 4, 1), 256, 0, stream>>>(
        x_bf, Win_bf, b_in, te, nullptr, h_bf, BB * TT, CC, CC, 1.0f);
    // 2) keysT + valsT in one launch   [4096 blocks]
    k_transpose2<<<4096, 256, 0, stream>>>(keys, keysT, vals, valsT);
    // 3) scores (bf16) -> attnb   [128x128, 2048 blocks]
    k_gemm<128, 128, 3><<<dim3(8, 16, BB), 256, 0, stream>>>(
        h_bf, keysT, nullptr, nullptr, nullptr, attnb, TT, SS, EE, 1.0f);
    // 4) softmax: wave-per-row, barrier-free   [4096 blocks]
    k_softmax<<<BB * TT / 4, 256, 0, stream>>>(attn, attnb);
    // 5) x_mean partials from bf16 attn   [512 blocks]
    k_xmean_part<<<dim3(XCH, BB), 256, 0, stream>>>(attnb, part);
    // 6) DPP chain (k_ns zeroes klp for the k_bfgm_kl atomics)
    k_ns<<<dim3(NSUB, BB), 256, 0, stream>>>(vals, part, ns, aa, klp);
    k_L<<<dim3(NSUB, BB), 128, 0, stream>>>(ns, aa, Lm);
    k_bfgm_kl<<<BB, 256, 0, stream>>>(Lm, part, klp);
    // 7) mid_bf = bf16((attn @ enc_values) * sqrt(S))   [64x128, 512 blocks]
    k_gemm<64, 128, 3><<<dim3(16, 2, BB), 256, 0, stream>>>(
        attnb, valsT, nullptr, nullptr, nullptr, mid_bf, TT, EE, SS, SQRT_S);
    // 8) out = (mid @ W_out^T + b_out + x) * sqrt(.5)   [64x64, 1024 blocks]
    k_gemm<64, 64, 1><<<dim3(256, 4, 1), 256, 0, stream>>>(
        mid_bf, Wout_bf, b_out, x, outp, nullptr, BB * TT, CC, CC, 1.0f);
}

// Round 8
// 443.083 us; speedup vs baseline: 1.1100x; 1.0385x over previous
//
#include <hip/hip_runtime.h>
#include <math.h>

#define BB 16
#define TT 1024
#define SS 2048
#define CC 256
#define EE 256
#define NSUB 103        // (SS-1)/STRIDE + 1
#define MAXS 20
#define STRIDE_ 20
#define XCH 32          // t-chunks for xmean partials (TT/XCH = 32 rows each)

static constexpr float RSQRT2  = 0.70710678118654752440f;   // sqrt(0.5)
static constexpr float SQRT_S  = 45.25483399593904f;        // s*sqrt(1/s) = sqrt(2048)
static constexpr float GNORM   = 0.13298076013381093f;      // 1/(sqrt(2*pi)*3)
static constexpr float INV2S2  = 0.055555555555555555f;     // 1/(2*sigma^2)

typedef __attribute__((ext_vector_type(8))) __bf16 bf16x8;
typedef __attribute__((ext_vector_type(4))) float  f32x4;

__device__ __forceinline__ float wave_sum(float v) {
    #pragma unroll
    for (int o = 32; o; o >>= 1) v += __shfl_down(v, o);
    return v;
}
__device__ __forceinline__ float wave_max(float v) {
    #pragma unroll
    for (int o = 32; o; o >>= 1) v = fmaxf(v, __shfl_down(v, o));
    return v;
}
__device__ __forceinline__ unsigned short f2bf(float f) {   // RNE
    unsigned int u = __float_as_uint(f);
    u = (u + 0x7FFFu + ((u >> 16) & 1u)) >> 16;
    return (unsigned short)u;
}
__device__ __forceinline__ float bf2f(unsigned short s) {
    return __uint_as_float(((unsigned int)s) << 16);
}

#define GLD_LDS16(g, l) __builtin_amdgcn_global_load_lds(                      \
    (const __attribute__((address_space(1))) void*)(g),                        \
    (__attribute__((address_space(3))) void*)(l), 16, 0, 0)

// fp32 -> bf16 cast over three disjoint buffers in one launch.
__global__ __launch_bounds__(256) void k_cast3(
    const float* __restrict__ a,  unsigned short* __restrict__ oa, int na,
    const float* __restrict__ b2, unsigned short* __restrict__ ob, int nb,
    const float* __restrict__ c2, unsigned short* __restrict__ oc, int nc)
{
    int i = blockIdx.x * 256 + threadIdx.x;
    const float* in; unsigned short* out;
    if (i < na)                { in = a;  out = oa; }
    else if (i < na + nb)      { in = b2; out = ob; i -= na; }
    else if (i < na + nb + nc) { in = c2; out = oc; i -= na + nb; }
    else return;
    const float4 v = reinterpret_cast<const float4*>(in)[i];
    union { unsigned short u[4]; unsigned long long v8; } pk;
    pk.u[0] = f2bf(v.x); pk.u[1] = f2bf(v.y);
    pk.u[2] = f2bf(v.z); pk.u[3] = f2bf(v.w);
    reinterpret_cast<unsigned long long*>(out)[i] = pk.v8;
}

// Both input transposes (keys and vals) in ONE launch of 4096 blocks.
// fp32 [Bz][R][Cc] -> bf16 [Bz][Cc][R].
__global__ __launch_bounds__(256) void k_transpose2(
    const float* __restrict__ keys, unsigned short* __restrict__ keysT,
    const float* __restrict__ vals, unsigned short* __restrict__ valsT)
{
    __shared__ float t[64][65];
    const int id = blockIdx.x;
    const float* in; unsigned short* out;
    int R, Cc, bx, by, b;
    if (id < 2048) {
        in = keys; out = keysT; R = EE; Cc = SS;
        bx = id & 3; by = (id >> 2) & 31; b = id >> 7;
    } else {
        const int id2 = id - 2048;
        in = vals; out = valsT; R = SS; Cc = EE;
        bx = id2 & 31; by = (id2 >> 5) & 3; b = id2 >> 7;
    }
    const int r0 = bx * 64, c0 = by * 64;
    const float* ip = in + (size_t)b * R * Cc;
    unsigned short* op = out + (size_t)b * R * Cc;
    const int tx = threadIdx.x & 63, ty = threadIdx.x >> 6;  // ty in [0,4)
    #pragma unroll
    for (int i = 0; i < 16; ++i)
        t[ty + 4 * i][tx] = ip[(size_t)(r0 + ty + 4 * i) * Cc + c0 + tx];
    __syncthreads();
    #pragma unroll
    for (int i = 0; i < 16; ++i)
        op[(size_t)(c0 + ty + 4 * i) * R + r0 + tx] = f2bf(t[tx][ty + 4 * i]);
}

// ---------------------------------------------------------------------------
// Unified bf16 MFMA GEMM (R5-proven): BK=64, XOR-swizzled LDS (pre-swizzled
// global source column, linear global_load_lds dest; reads apply the same
// XOR), XCD-chunked bijective blockIdx swizzle. 4 waves, 2x2 wave grid.
// MODE 0: Of = acc*scale
// MODE 1: Of = (acc + bias[n] + add[m,n])*RSQRT2
// MODE 2: Ob = bf16((acc + bias[n] + add[m,n])*RSQRT2)
// MODE 3: Ob = bf16(acc*scale)
// ---------------------------------------------------------------------------
template<int BM, int BN, int MODE>
__global__ __launch_bounds__(256) void k_gemm(
    const unsigned short* __restrict__ Abase,
    const unsigned short* __restrict__ Btbase,
    const float* __restrict__ bias, const float* __restrict__ add,
    float* __restrict__ Obase, unsigned short* __restrict__ Obbase,
    int M, int Nn, int K, float scale)
{
    constexpr int BK = 64;
    constexpr int AR = BM / 32;
    constexpr int BR = BN / 32;
    constexpr int WM = BM / 2, WN = BN / 2;
    constexpr int MI = WM / 16, NJ = WN / 16;

    __shared__ unsigned short As[BM * BK];
    __shared__ unsigned short Bs[BN * BK];

    const int nwg = gridDim.x * gridDim.y * gridDim.z;
    int l = blockIdx.x + gridDim.x * (blockIdx.y + gridDim.y * blockIdx.z);
    if ((nwg & 7) == 0) l = (l & 7) * (nwg >> 3) + (l >> 3);
    const int bx = l % gridDim.x; l /= gridDim.x;
    const int by = l % gridDim.y;
    const int b  = l / gridDim.y;

    const int m0 = bx * BM;
    const int n0 = by * BN;
    const unsigned short* A  = Abase  + (size_t)b * M  * K;
    const unsigned short* Bt = Btbase + (size_t)b * Nn * K;

    const int tid  = threadIdx.x;
    const int w    = tid >> 6;
    const int lane = tid & 63;
    const int wm   = w & 1, wn = w >> 1;

    const int sr  = tid >> 3;
    const int skb = ((tid & 7) << 4) ^ ((sr & 7) << 4);
    const unsigned short* ga[AR];
    const unsigned short* gb[BR];
    #pragma unroll
    for (int p = 0; p < AR; ++p)
        ga[p] = A + (size_t)(m0 + p * 32 + sr) * K + (skb >> 1);
    #pragma unroll
    for (int p = 0; p < BR; ++p)
        gb[p] = Bt + (size_t)(n0 + p * 32 + sr) * K + (skb >> 1);

    const int fr = lane & 15;
    const int qb = (lane >> 4) << 4;

    f32x4 acc[MI][NJ];
    #pragma unroll
    for (int i = 0; i < MI; ++i)
        #pragma unroll
        for (int j = 0; j < NJ; ++j)
            acc[i][j] = (f32x4){0.f, 0.f, 0.f, 0.f};

    for (int k0 = 0; k0 < K; k0 += BK) {
        #pragma unroll
        for (int p = 0; p < AR; ++p) GLD_LDS16(ga[p], As + p * 2048 + w * 512);
        #pragma unroll
        for (int p = 0; p < BR; ++p) GLD_LDS16(gb[p], Bs + p * 2048 + w * 512);
        #pragma unroll
        for (int p = 0; p < AR; ++p) ga[p] += BK;
        #pragma unroll
        for (int p = 0; p < BR; ++p) gb[p] += BK;
        __syncthreads();
        #pragma unroll
        for (int c = 0; c < 2; ++c) {
            bf16x8 af[MI], bf[NJ];
            #pragma unroll
            for (int i = 0; i < MI; ++i) {
                const int row = wm * WM + i * 16 + fr;
                const int byt = row * 128 + ((c * 64 + qb) ^ ((row & 7) << 4));
                af[i] = *reinterpret_cast<const bf16x8*>(
                            reinterpret_cast<const char*>(As) + byt);
            }
            #pragma unroll
            for (int j = 0; j < NJ; ++j) {
                const int row = wn * WN + j * 16 + fr;
                const int byt = row * 128 + ((c * 64 + qb) ^ ((row & 7) << 4));
                bf[j] = *reinterpret_cast<const bf16x8*>(
                            reinterpret_cast<const char*>(Bs) + byt);
            }
            #pragma unroll
            for (int i = 0; i < MI; ++i)
                #pragma unroll
                for (int j = 0; j < NJ; ++j)
                    acc[i][j] = __builtin_amdgcn_mfma_f32_16x16x32_bf16(af[i], bf[j], acc[i][j], 0, 0, 0);
        }
        __syncthreads();
    }

    float* Of = (MODE == 0 || MODE == 1) ? Obase + (size_t)b * M * Nn : nullptr;
    unsigned short* Ob = (MODE == 2 || MODE == 3) ? Obbase + (size_t)b * M * Nn : nullptr;
    const int rb = (lane >> 4) * 4;
    #pragma unroll
    for (int i = 0; i < MI; ++i)
        #pragma unroll
        for (int j = 0; j < NJ; ++j) {
            const int n = n0 + wn * WN + j * 16 + fr;
            #pragma unroll
            for (int r2 = 0; r2 < 4; ++r2) {
                const int m = m0 + wm * WM + i * 16 + rb + r2;
                const size_t idx = (size_t)m * Nn + n;
                if (MODE == 0) {
                    Of[idx] = acc[i][j][r2] * scale;
                } else if (MODE == 1) {
                    Of[idx] = (acc[i][j][r2] + bias[n] + add[idx]) * RSQRT2;
                } else if (MODE == 2) {
                    Ob[idx] = f2bf((acc[i][j][r2] + bias[n] + add[idx]) * RSQRT2);
                } else {
                    Ob[idx] = f2bf(acc[i][j][r2] * scale);
                }
            }
        }
}

// Row softmax over S=2048, ONE WAVE PER ROW (4 rows per 256-thr block).
// Zero barriers, zero LDS. Input: bf16 scores in attnb;
// output: fp32 attn + bf16 attnb in place. grid BB*TT/4.
__global__ __launch_bounds__(256) void k_softmax(float* __restrict__ attn,
                                                 unsigned short* __restrict__ attnb)
{
    const int row  = blockIdx.x * 4 + (threadIdx.x >> 6);
    const int lane = threadIdx.x & 63;
    float* p = attn + (size_t)row * SS;
    unsigned short* pb = attnb + (size_t)row * SS;

    float v[32];
    #pragma unroll
    for (int s = 0; s < 4; ++s) {
        union { unsigned short u[8]; uint4 q; } ld;
        ld.q = *reinterpret_cast<const uint4*>(&pb[s * 512 + lane * 8]);
        #pragma unroll
        for (int i = 0; i < 8; ++i) v[s * 8 + i] = bf2f(ld.u[i]);
    }
    float mx = v[0];
    #pragma unroll
    for (int i = 1; i < 32; ++i) mx = fmaxf(mx, v[i]);
    #pragma unroll
    for (int o = 32; o; o >>= 1) mx = fmaxf(mx, __shfl_xor(mx, o));
    float s = 0.f;
    #pragma unroll
    for (int i = 0; i < 32; ++i) { v[i] = expf(v[i] - mx); s += v[i]; }
    #pragma unroll
    for (int o = 32; o; o >>= 1) s += __shfl_xor(s, o);
    const float inv = 1.0f / s;
    #pragma unroll
    for (int seg = 0; seg < 4; ++seg) {
        float4 o0, o1;
        o0.x = v[seg * 8 + 0] * inv; o0.y = v[seg * 8 + 1] * inv;
        o0.z = v[seg * 8 + 2] * inv; o0.w = v[seg * 8 + 3] * inv;
        o1.x = v[seg * 8 + 4] * inv; o1.y = v[seg * 8 + 5] * inv;
        o1.z = v[seg * 8 + 6] * inv; o1.w = v[seg * 8 + 7] * inv;
        *reinterpret_cast<float4*>(&p[seg * 512 + lane * 8])     = o0;
        *reinterpret_cast<float4*>(&p[seg * 512 + lane * 8 + 4]) = o1;
        union { unsigned short u[8]; uint4 q; } pk;
        pk.u[0] = f2bf(o0.x); pk.u[1] = f2bf(o0.y); pk.u[2] = f2bf(o0.z); pk.u[3] = f2bf(o0.w);
        pk.u[4] = f2bf(o1.x); pk.u[5] = f2bf(o1.y); pk.u[6] = f2bf(o1.z); pk.u[7] = f2bf(o1.w);
        *reinterpret_cast<uint4*>(&pb[seg * 512 + lane * 8]) = pk.q;
    }
}

// Partial t-sums of attn: part[b][c][s] = sum_{t in chunk c} attnb[b][t][s].
// Also zeroes klp (stream-ordered before k_bfgm_kl's atomic).
__global__ __launch_bounds__(256) void k_xmean_part(const unsigned short* __restrict__ attnb,
                                                    float* __restrict__ part,
                                                    float* __restrict__ klp)
{
    const int c = blockIdx.x, b = blockIdx.y;
    if (c == 0 && b == 0 && threadIdx.x == 0) klp[0] = 0.0f;
    const unsigned short* p = attnb + ((size_t)b * TT + (size_t)c * (TT / XCH)) * SS
                              + threadIdx.x * 8;
    float acc[8] = {0.f, 0.f, 0.f, 0.f, 0.f, 0.f, 0.f, 0.f};
    #pragma unroll 8
    for (int t = 0; t < TT / XCH; ++t) {
        union { unsigned short u[8]; uint4 v4; } ld;
        ld.v4 = *reinterpret_cast<const uint4*>(p + (size_t)t * SS);
        #pragma unroll
        for (int i = 0; i < 8; ++i) acc[i] += bf2f(ld.u[i]);
    }
    float* o = part + ((size_t)b * XCH + c) * SS + threadIdx.x * 8;
    #pragma unroll
    for (int i = 0; i < 8; ++i) o[i] = acc[i];
}

// L[b,i,j] = aa_i*aa_j * dot(ev_i,ev_j)/(|ev_i||ev_j|), rows i*STRIDE of
// enc_values. Replaces k_ns + k_L: no ns materialization; float4 loads;
// |ev_j| fused into the same load stream. grid (NSUB, BB), 128 thr.
__global__ __launch_bounds__(128) void k_L_direct(const float* __restrict__ ev,
                                                  const float* __restrict__ part,
                                                  float* __restrict__ Lm)
{
    const int i = blockIdx.x, b = blockIdx.y;
    const int tid = threadIdx.x;
    __shared__ float evi[EE];
    __shared__ float aaS[NSUB];
    __shared__ float w[2];
    // stage ev_i + |ev_i|
    const float* rowi = ev + ((size_t)b * SS + (size_t)i * STRIDE_) * EE;
    const float v0 = rowi[tid], v1 = rowi[tid + 128];
    evi[tid] = v0; evi[tid + 128] = v1;
    const float r = wave_sum(v0 * v0 + v1 * v1);
    if ((tid & 63) == 0) w[tid >> 6] = r;
    // aa_j for all j (from xmean partials)
    if (tid < NSUB) {
        float s = 0.f;
        #pragma unroll 8
        for (int c2 = 0; c2 < XCH; ++c2)
            s += part[((size_t)b * XCH + c2) * SS + tid * STRIDE_];
        aaS[tid] = s * (1.0f / TT);
    }
    __syncthreads();
    const float nrmi = sqrtf(w[0] + w[1]);
    const float ai = aaS[i];
    for (int j = tid; j < NSUB; j += 128) {
        const float* rj = ev + ((size_t)b * SS + (size_t)j * STRIDE_) * EE;
        float d = 0.f, n2 = 0.f;
        #pragma unroll 4
        for (int e = 0; e < EE; e += 4) {
            const float4 a4 = *reinterpret_cast<const float4*>(&evi[e]);
            const float4 b4 = *reinterpret_cast<const float4*>(&rj[e]);
            d  += a4.x * b4.x + a4.y * b4.y + a4.z * b4.z + a4.w * b4.w;
            n2 += b4.x * b4.x + b4.y * b4.y + b4.z * b4.z + b4.w * b4.w;
        }
        Lm[((size_t)b * NSUB + i) * NSUB + j] = d * ai * aaS[j] / (nrmi * sqrtf(n2));
    }
}

// Greedy MAP DPP (Cholesky, SINGLE WAVE, barrier-free) + dist + KL.
// One block (256 thr) per batch: wave 0 holds 2 items/lane in registers
// (D, mask), argmax = pure shfl butterfly; Cm in LDS with a
// __threadfence_block after each column write (same-wave LDS RAW fence).
// xm loads issued by all threads BEFORE the serial section to overlap it.
__global__ __launch_bounds__(256) void k_bfgm_kl(const float* __restrict__ Lm,
                                                 const float* __restrict__ part,
                                                 float* __restrict__ outkl)
{
    const int b = blockIdx.x;
    const int tid = threadIdx.x;
    const float* L = Lm + (size_t)b * NSUB * NSUB;
    __shared__ float CmL[128 * 21];
    __shared__ float musS[MAXS];
    __shared__ float w[4];

    // prefetch xm (independent of Cholesky; overlaps wave-0 serial work)
    float xm[8];
    #pragma unroll
    for (int i = 0; i < 8; ++i) {
        float s = 0.f;
        #pragma unroll 8
        for (int c2 = 0; c2 < XCH; ++c2)
            s += part[((size_t)b * XCH + c2) * SS + tid + (i << 8)];
        xm[i] = s * (1.0f / TT);
    }

    if (tid < 64) {
        const int i0 = tid, i1 = tid + 64;
        const bool a1 = (i1 < NSUB);
        float D0 = L[(size_t)i0 * NSUB + i0];
        float D1 = a1 ? L[(size_t)i1 * NSUB + i1] : 0.0f;
        float m0 = 1.0f, m1 = a1 ? 1.0f : 0.0f;
        #pragma unroll
        for (int k = 0; k < MAXS; ++k) { CmL[i0 * 21 + k] = 0.0f; CmL[i1 * 21 + k] = 0.0f; }
        #pragma unroll 1
        for (int t = 0; t < MAXS; ++t) {
            // argmax of log(D*mask); NaN -> +inf (numpy argmax NaN-wins);
            // ties -> lowest index (i0 < i1 always, so pair-tie picks i0)
            float k0 = logf(D0 * m0); if (isnan(k0)) k0 = INFINITY;
            float k1 = a1 ? logf(D1 * m1) : -INFINITY; if (isnan(k1)) k1 = INFINITY;
            float v = k0; int idx = i0;
            if (k1 > v) { v = k1; idx = i1; }
            #pragma unroll
            for (int o = 32; o; o >>= 1) {
                const float ov = __shfl_down(v, o);
                const int   oi = __shfl_down(idx, o);
                if (ov > v || (ov == v && oi < idx)) { v = ov; idx = oi; }
            }
            const int J = __shfl(idx, 0);          // uniform
            if (J == i0) m0 = 0.0f;
            if (J == i1) m1 = 0.0f;
            if (tid == 0) musS[t] = (float)J;
            if (t == MAXS - 1) break;
            // Cholesky update: writes column t+1 (column 0 stays zero)
            const float Dsel = (J >= 64) ? D1 : D0;
            const float dj = __shfl(Dsel, J & 63);
            const float Lj0 = L[(size_t)J * NSUB + i0];
            const float Lj1 = a1 ? L[(size_t)J * NSUB + i1] : 0.0f;
            float cd0 = 0.0f, cd1 = 0.0f;
            for (int k = 1; k <= t; ++k) {         // cols >t are zero
                const float cjk = CmL[J * 21 + k]; // broadcast read
                cd0 += CmL[i0 * 21 + k] * cjk;
                cd1 += CmL[i1 * 21 + k] * cjk;
            }
            const float e0 = (Lj0 - cd0) / dj * m0;
            const float e1 = a1 ? (Lj1 - cd1) / dj * m1 : 0.0f;
            CmL[i0 * 21 + t + 1] = e0;
            CmL[i1 * 21 + t + 1] = e1;
            __threadfence_block();                 // cross-lane LDS visibility
            D0 -= e0 * e0;
            D1 -= e1 * e1;
        }
    }
    __syncthreads();

    // ---- dist softmax + KL (all 256 threads) ----
    float g[8];
    float mx = -INFINITY;
    #pragma unroll
    for (int i = 0; i < 8; ++i) {
        const float s = (float)(tid + (i << 8));
        float acc = 0.f;
        #pragma unroll
        for (int m = 0; m < MAXS; ++m) { const float z = s - musS[m]; acc += expf(-(z * z) * INV2S2); }
        g[i] = acc * GNORM;
        mx = fmaxf(mx, g[i]);
    }
    float wm = wave_max(mx);
    if ((tid & 63) == 0) w[tid >> 6] = wm;
    __syncthreads();
    const float m = fmaxf(fmaxf(w[0], w[1]), fmaxf(w[2], w[3]));
    float sum = 0.f;
    #pragma unroll
    for (int i = 0; i < 8; ++i) { g[i] = expf(g[i] - m); sum += g[i]; }
    __syncthreads();
    float wsv = wave_sum(sum);
    if ((tid & 63) == 0) w[tid >> 6] = wsv;
    __syncthreads();
    const float inv = 1.0f / (w[0] + w[1] + w[2] + w[3]);
    float acc2 = 0.f;
    #pragma unroll
    for (int i = 0; i < 8; ++i)
        acc2 += xm[i] * (logf(xm[i]) - g[i] * inv);
    __syncthreads();
    float wp = wave_sum(acc2);
    if ((tid & 63) == 0) w[tid >> 6] = wp;
    __syncthreads();
    if (tid == 0) atomicAdd(outkl, -(w[0] + w[1] + w[2] + w[3]));
}

extern "C" void kernel_launch(void* const* d_in, const int* in_sizes, int n_in,
                              void* d_out, int out_size, void* d_ws, size_t ws_size,
                              hipStream_t stream)
{
    const float* x     = (const float*)d_in[0];   // (B,T,C)
    const float* te    = (const float*)d_in[1];   // (B,T,E)
    const float* keys  = (const float*)d_in[2];   // (B,E,S)
    const float* vals  = (const float*)d_in[3];   // (B,S,E)
    const float* W_in  = (const float*)d_in[4];   // (E,C)
    const float* b_in  = (const float*)d_in[5];   // (E)
    const float* W_out = (const float*)d_in[6];   // (C,E)
    const float* b_out = (const float*)d_in[7];   // (C)

    float* outp = (float*)d_out;                       // (B,T,C)
    float* attn = outp + (size_t)BB * TT * CC;         // (B,T,S) fp32
    float* klp  = attn + (size_t)BB * TT * SS;         // scalar

    // workspace
    unsigned short* X       = (unsigned short*)d_ws;
    unsigned short* x_bf    = X;                                       // B*T*C
    unsigned short* Win_bf  = x_bf   + (size_t)BB * TT * CC;           // E*C
    unsigned short* Wout_bf = Win_bf + (size_t)EE * CC;                // C*E
    unsigned short* h_bf    = Wout_bf+ (size_t)CC * EE;                // B*T*E
    unsigned short* keysT   = h_bf   + (size_t)BB * TT * EE;           // B*S*E
    unsigned short* valsT   = keysT  + (size_t)BB * SS * EE;           // B*E*S
    unsigned short* attnb   = valsT  + (size_t)BB * EE * SS;           // B*T*S (scores, then attn)
    unsigned short* mid_bf  = attnb  + (size_t)BB * TT * SS;           // B*T*E
    float* fws   = (float*)(mid_bf + (size_t)BB * TT * EE + 8);
    float* part  = fws;                                  // (B,XCH,S)
    float* Lm    = part  + (size_t)BB * XCH * SS;        // (B,N,N)

    // casts (x, W_in, W_out in one launch)
    {
        const int na = BB * TT * CC / 4, nb = EE * CC / 4, nc = CC * EE / 4;
        const int blocks = (na + nb + nc + 255) / 256;
        k_cast3<<<blocks, 256, 0, stream>>>(x, x_bf, na, W_in, Win_bf, nb, W_out, Wout_bf, nc);
    }
    // 1) h_bf = bf16((x @ W_in^T + b_in + te) * sqrt(.5))   [64x64, 1024 blocks]
    k_gemm<64, 64, 2><<<dim3(256, 4, 1), 256, 0, stream>>>(
        x_bf, Win_bf, b_in, te, nullptr, h_bf, BB * TT, CC, CC, 1.0f);
    // 2) keysT + valsT in one launch   [4096 blocks]
    k_transpose2<<<4096, 256, 0, stream>>>(keys, keysT, vals, valsT);
    // 3) scores (bf16) -> attnb   [128x128, 2048 blocks]
    k_gemm<128, 128, 3><<<dim3(8, 16, BB), 256, 0, stream>>>(
        h_bf, keysT, nullptr, nullptr, nullptr, attnb, TT, SS, EE, 1.0f);
    // 4) softmax: wave-per-row, barrier-free   [4096 blocks]
    k_softmax<<<BB * TT / 4, 256, 0, stream>>>(attn, attnb);
    // 5) x_mean partials (also zeroes klp)   [512 blocks]
    k_xmean_part<<<dim3(XCH, BB), 256, 0, stream>>>(attnb, part, klp);
    // 6) DPP chain
    k_L_direct<<<dim3(NSUB, BB), 128, 0, stream>>>(vals, part, Lm);
    k_bfgm_kl<<<BB, 256, 0, stream>>>(Lm, part, klp);
    // 7) mid_bf = bf16((attn @ enc_values) * sqrt(S))   [64x128, 512 blocks]
    k_gemm<64, 128, 3><<<dim3(16, 2, BB), 256, 0, stream>>>(
        attnb, valsT, nullptr, nullptr, nullptr, mid_bf, TT, EE, SS, SQRT_S);
    // 8) out = (mid @ W_out^T + b_out + x) * sqrt(.5)   [64x64, 1024 blocks]
    k_gemm<64, 64, 1><<<dim3(256, 4, 1), 256, 0, stream>>>(
        mid_bf, Wout_bf, b_out, x, outp, nullptr, BB * TT, CC, CC, 1.0f);
}